// Round 3
// baseline (282.608 us; speedup 1.0000x reference)
//
#include <hip/hip_runtime.h>
#include <cmath>
#include <cstdint>

// Problem constants (from reference)
constexpr int B_ = 8, N_ = 1024, M_ = 512, D_ = 128, S_ = 1536, L_ = 6, DFF_ = 512;
constexpr int ROWS = B_ * S_;    // 12288
constexpr int MAXDEG = 64;       // max attention row degree (actual ~4-25)
constexpr int LKEY = 32;         // LDS-cached keys per row
constexpr int RPB  = 48;         // rows per block
constexpr int NBLK = ROWS / RPB; // 256 persistent blocks (1/CU, all resident)
constexpr int BPB  = S_ / RPB;   // 32 blocks per batch (barrier group)
constexpr int NTILE = 12;        // weight tiles per layer, in stage order
constexpr int TILE  = 128 * 128; // halfwords per tile (LDS image, 32 KB)
constexpr int KVSZ  = ROWS * 256;// halfwords per kv layer-buffer
constexpr int WBLK  = L_ * NTILE * 2;  // 144 wconv half-tile blocks
constexpr int ABLK  = 128;             // adj blocks (4 check rows each)
constexpr int WLAYER = NTILE * TILE;   // 196608 halfwords per layer

typedef __bf16 bf16x8 __attribute__((ext_vector_type(8)));
typedef float  f32x4  __attribute__((ext_vector_type(4)));
typedef unsigned short u16x8 __attribute__((ext_vector_type(8)));

__device__ inline unsigned short f2bf(float f) {  // native hw RNE convert
  return __builtin_bit_cast(unsigned short, (__bf16)f);
}
__device__ inline float bf2f(unsigned short u) {
  return __uint_as_float(((unsigned)u) << 16);
}

// Direct global->LDS async copy, 16 B/lane (m97's lever).
__device__ __forceinline__ void async_ld16(const unsigned short* g, unsigned short* l) {
  __builtin_amdgcn_global_load_lds(
      (const __attribute__((address_space(1))) unsigned int*)(uintptr_t)g,
      (__attribute__((address_space(3))) unsigned int*)(unsigned)(uintptr_t)l,
      16, 0, 0);
}
// Issue one 32 KB tile (pre-swizzled LDS image) into a Bs buffer.
// NOTE: tile is split across all 6 waves -> every issue->use path MUST have
// >=1 __syncthreads between them (only a barrier drains other waves' vmcnt).
__device__ __forceinline__ void issue_tile(const unsigned short* tp, unsigned short* bs,
                                           int w, int lane) {
  for (int c = w; c < 32; c += 6)
    async_ld16(tp + c * 512 + lane * 8, bs + c * 512);
}

// ---------------------------------------------------------------------------
// Combined setup kernel (adjcnt/bcnt pre-zeroed via hipMemsetAsync):
//  blocks [0, WBLK): weight convert, one 64-kd half-tile each, via LDS
//    transpose staging. Tile/stage order: [0]=Wk^T [1]=Wv^T [2]=Wq^T [3]=Wo^T
//    [4+2c]=W1^T chunk c [5+2c]=W2^T chunk c.
//    Image: tile[rr*128 + ((cc^(rr&15))<<3) + e] = W^T[rr][cc*8+e].
//  blocks [WBLK, WBLK+ABLK): adjacency from pcm ROWS, both Tanner directions
//    + self-edges via atomic append (order irrelevant: softmax and mod-2
//    syndrome are permutation-invariant).
// ---------------------------------------------------------------------------
__global__ void setup_kernel(const float* __restrict__ Wq, const float* __restrict__ Wk,
                             const float* __restrict__ Wv, const float* __restrict__ Wo,
                             const float* __restrict__ W1, const float* __restrict__ W2,
                             unsigned short* __restrict__ out, const int* __restrict__ pcm,
                             int* __restrict__ adj, int* __restrict__ adjcnt) {
  int bid = blockIdx.x;
  if (bid >= WBLK) {  // ---- adjacency blocks: 4 check rows + 12 self-rows ----
    int ab = bid - WBLK;
    int c0 = ab * 4, lane = threadIdx.x & 63, sub = threadIdx.x >> 6;  // 4 subrows
    if (threadIdx.x < 12) {
      int s = ab * 12 + threadIdx.x;
      int slot = atomicAdd(&adjcnt[s], 1);
      if (slot < MAXDEG) adj[s * MAXDEG + slot] = s;
    }
    int c = c0 + sub;
    const int* row = pcm + c * N_;
    for (int base = 0; base < N_; base += 64) {
      int k = base + lane;
      if (row[k] != 0) {
        int s1 = atomicAdd(&adjcnt[N_ + c], 1);
        if (s1 < MAXDEG) adj[(N_ + c) * MAXDEG + s1] = k;
        int s2 = atomicAdd(&adjcnt[k], 1);
        if (s2 < MAXDEG) adj[k * MAXDEG + s2] = N_ + c;
      }
    }
    return;
  }
  // ---- weight-convert blocks ----
  __shared__ unsigned short tl[64 * 130];  // +2 pad breaks transpose conflicts
  int tb = bid >> 1, half = bid & 1;
  int l = tb / NTILE, tile = tb % NTILE;
  const int kd0 = half * 64;
  const float* src;
  int rstride, coff = 0;
  if (tile == 0)      { src = Wk + (size_t)l * D_ * D_;  rstride = D_; }
  else if (tile == 1) { src = Wv + (size_t)l * D_ * D_;  rstride = D_; }
  else if (tile == 2) { src = Wq + (size_t)l * D_ * D_;  rstride = D_; }
  else if (tile == 3) { src = Wo + (size_t)l * D_ * D_;  rstride = D_; }
  else {
    int c = (tile - 4) >> 1;
    if (((tile - 4) & 1) == 0) { src = W1 + (size_t)l * D_ * DFF_; rstride = DFF_; coff = c * 128; }
    else                       { src = W2 + (size_t)l * DFF_ * D_ + (size_t)c * 128 * D_; rstride = D_; }
  }
  for (int i = threadIdx.x; i < 8192; i += 256) {
    int kd = i >> 7, rr = i & 127;
    tl[kd * 130 + rr] = f2bf(src[(size_t)(kd0 + kd) * rstride + coff + rr]);
  }
  __syncthreads();
  unsigned short* o = out + (size_t)tb * TILE;
  for (int i = threadIdx.x; i < 8192; i += 256) {
    int rr = i >> 6;
    int kloc = i & 63;
    int kd = kd0 + kloc;
    int cc = kd >> 3, e = kd & 7;
    int sw = cc ^ (rr & 15);
    o[rr * 128 + (sw << 3) + e] = tl[kloc * 130 + rr];
  }
}

// ---------------------------------------------------------------------------
// MFMA helpers, precomputed halfword offsets (swizzle derived once/thread).
// Wave tile = 16 rows x 64 cols (4 tiles of 16x16), K=128 in 4 steps of 32.
// ---------------------------------------------------------------------------
__device__ __forceinline__ void mfmaS(const unsigned short* A, const unsigned short* Bt,
                                      const int (&ao)[4], const int (&bo)[16],
                                      f32x4 (&acc)[4]) {
#pragma unroll
  for (int kk = 0; kk < 4; ++kk) {
    bf16x8 a = __builtin_bit_cast(bf16x8, *(const uint4*)&A[ao[kk]]);
#pragma unroll
    for (int ct = 0; ct < 4; ++ct) {
      bf16x8 bb = __builtin_bit_cast(bf16x8, *(const uint4*)&Bt[bo[kk * 4 + ct]]);
      acc[ct] = __builtin_amdgcn_mfma_f32_16x16x32_bf16(a, bb, acc[ct], 0, 0, 0);
    }
  }
}
// Fused K+V stage: each A-fragment read once, feeds both B tiles.
__device__ __forceinline__ void mfmaKV(const unsigned short* A, const unsigned short* Kt,
                                       const unsigned short* Vt, const int (&ao)[4],
                                       const int (&bo)[16], f32x4 (&aK)[4], f32x4 (&aV)[4]) {
#pragma unroll
  for (int kk = 0; kk < 4; ++kk) {
    bf16x8 a = __builtin_bit_cast(bf16x8, *(const uint4*)&A[ao[kk]]);
#pragma unroll
    for (int ct = 0; ct < 4; ++ct) {
      bf16x8 bk = __builtin_bit_cast(bf16x8, *(const uint4*)&Kt[bo[kk * 4 + ct]]);
      bf16x8 bv = __builtin_bit_cast(bf16x8, *(const uint4*)&Vt[bo[kk * 4 + ct]]);
      aK[ct] = __builtin_amdgcn_mfma_f32_16x16x32_bf16(a, bk, aK[ct], 0, 0, 0);
      aV[ct] = __builtin_amdgcn_mfma_f32_16x16x32_bf16(a, bv, aV[ct], 0, 0, 0);
    }
  }
}
template <bool RELU>
__device__ __forceinline__ void writeC(unsigned short* base, const int (&co)[16],
                                       const f32x4 (&acc)[4]) {
#pragma unroll
  for (int ct = 0; ct < 4; ++ct)
#pragma unroll
    for (int i = 0; i < 4; ++i) {
      float v = acc[ct][i];
      if constexpr (RELU) v = fmaxf(v, 0.f);
      base[co[ct * 4 + i]] = f2bf(v);
    }
}

// ---------------------------------------------------------------------------
// Persistent mega-kernel: x-init + all 6 layers + fc head.
// grid = 256 blocks x 384 thr (6 waves); block owns 48 rows; 1 block/CU.
// XCD affinity: batch = blockIdx%8 -> all 32 blocks of a batch on one XCD
// (round-robin dispatch), so kv stores/reads + barrier atomics are L2-local.
// KV store is wave-private (each wave reads back only its own written
// quadrant) -> no block-wide post-QKV sync; store drain hides under Q MFMA.
// FFN: proven 2-sync ring (every issue->use crosses >=1 barrier; the round-1
// 1-sync variant raced on the W1(c+1) edge).
// LDS: As 12K + Bs 96K + Cs 12K + KVs 24K + red/keys ~8K ~= 152 KB.
// ---------------------------------------------------------------------------
__global__ void __launch_bounds__(384) mega_kernel(
    const float* __restrict__ r_t, const float* __restrict__ se,
    unsigned short* __restrict__ kvbase, const unsigned short* __restrict__ wbf,
    const float* __restrict__ g1, const float* __restrict__ b1,
    const float* __restrict__ g2, const float* __restrict__ b2,
    const int* __restrict__ tt, const float* __restrict__ table,
    const int* __restrict__ adj, const int* __restrict__ adjc,
    const float* __restrict__ fcw, const float* __restrict__ fcb,
    float* __restrict__ out, unsigned* barrier_cnt) {
  __shared__ unsigned short As[RPB * 128];      // 12 KB
  __shared__ unsigned short Bs[3][TILE];        // 96 KB (ring)
  __shared__ unsigned short Cs[RPB * 128];      // 12 KB (Q, then FFN hf)
  __shared__ unsigned short KVs[RPB * 256];     // 24 KB (K|V repack)
  __shared__ float red1[2][RPB], red2[2][RPB];
  __shared__ float nodeS[RPB];
  __shared__ int sKeys[RPB * LKEY];             // 6 KB
  __shared__ int sCnt[RPB];
  const int b = blockIdx.x & 7;                 // batch -> XCD (round-robin map)
  const int jblk = blockIdx.x >> 3;             // 0..31 within batch
  const int row0 = b * S_ + jblk * RPB;
  const int bS = b * S_;
  const int t = threadIdx.x, w = t >> 6, lane = t & 63, quad = lane >> 4, l16 = lane & 15;
  const int wr = w >> 1, wc = w & 1;
  const int rowbase = wr * 16, colbase = wc * 64;
  const int tbase = tt[b] * D_;
  unsigned* bcnt = barrier_cnt + b * 32;        // per-batch counter, 128 B apart

  // ---- precomputed swizzled LDS fragment offsets (halfwords) --------------
  int aoff[4], boff[16], cwo[16];
#pragma unroll
  for (int kk = 0; kk < 4; ++kk) {
    int row = rowbase + l16, cb = kk * 4 + quad;
    aoff[kk] = row * 128 + ((cb ^ (row & 15)) << 3);
#pragma unroll
    for (int ct = 0; ct < 4; ++ct) {
      int n = colbase + ct * 16 + l16;
      boff[kk * 4 + ct] = n * 128 + ((cb ^ (n & 15)) << 3);
    }
  }
#pragma unroll
  for (int ct = 0; ct < 4; ++ct)
#pragma unroll
    for (int i = 0; i < 4; ++i) {
      int rowL = rowbase + quad * 4 + i, col = colbase + ct * 16 + l16;
      cwo[ct * 4 + i] = rowL * 128 + (((col >> 3) ^ (rowL & 15)) << 3) + (col & 7);
    }
  float teR[4];
#pragma unroll
  for (int ct = 0; ct < 4; ++ct) teR[ct] = table[tbase + colbase + ct * 16 + l16];

  // prime the pipeline: layer-0 K,V,Q tiles -> Bs[0..2]
  issue_tile(wbf + 0 * TILE, Bs[0], w, lane);
  issue_tile(wbf + 1 * TILE, Bs[1], w, lane);
  issue_tile(wbf + 2 * TILE, Bs[2], w, lane);

  // ---- prologue: adjacency cache, node values (8 thr/row), x -> registers -
  if (t < RPB) {
    int c = adjc[row0 + t - bS];
    sCnt[t] = c < MAXDEG ? c : MAXDEG;
  }
  for (int i = t; i < RPB * LKEY; i += 384) {
    int r = i / LKEY, j = i % LKEY;
    sKeys[i] = adj[(row0 + r - bS) * MAXDEG + j];  // tail values unused
  }
  __syncthreads();
  {  // task = (row rL, slot p): 48 x 8 = 384
    const int rL = t >> 3, p = t & 7;
    const int s = row0 + rL - bS;
    float node;
    if (s < N_) {
      node = fabsf(r_t[b * N_ + s]);
    } else {
      const int cnt = sCnt[rL];
      float sum = 0.f;
      for (int j = p; j < cnt; j += 8) {
        int k = (j < LKEY) ? sKeys[rL * LKEY + j] : adj[s * MAXDEG + j];
        if (k < N_) {
          float r = r_t[b * N_ + k];
          sum += (r < 0.f) ? 1.f : (r > 0.f ? 0.f : 0.5f);  // bits = 0.5*(1-sign)
        }
      }
      sum += __shfl_xor(sum, 1, 16);
      sum += __shfl_xor(sum, 2, 16);
      sum += __shfl_xor(sum, 4, 16);
      node = fmodf(sum, 2.0f);
    }
    if (p == 0) nodeS[rL] = node;
  }
  __syncthreads();
  // persistent x in registers (MFMA C-layout): x = te * se * node
  f32x4 xreg[4];
#pragma unroll
  for (int ct = 0; ct < 4; ++ct)
#pragma unroll
    for (int i = 0; i < 4; ++i) {
      int rowL = rowbase + quad * 4 + i;
      int s = row0 + rowL - bS;
      int col = colbase + ct * 16 + l16;
      xreg[ct][i] = teR[ct] * se[(size_t)s * D_ + col] * nodeS[rowL];
    }

  constexpr int bufW1[4] = {1, 0, 2, 1};
  constexpr int bufW2[4] = {2, 1, 0, 2};

  for (int l = 0; l < L_; ++l) {
    const unsigned short* wt = wbf + (size_t)l * WLAYER;
    unsigned short* kv = kvbase + (size_t)l * KVSZ;
    const float* g1l = g1 + l * D_;
    const float* b1l = b1 + l * D_;
    const float* g2l = g2 + l * D_;
    const float* b2l = b2 + l * D_;
    float g1v[4], b1v[4], g2v[4], b2v[4];
#pragma unroll
    for (int ct = 0; ct < 4; ++ct) {
      int col = colbase + ct * 16 + l16;
      g1v[ct] = g1l[col]; b1v[ct] = b1l[col];
      g2v[ct] = g2l[col]; b2v[ct] = b2l[col];
    }

    // ------------- LN1 (one-pass var) on register x -> bf16 h in As --------
#pragma unroll
    for (int i = 0; i < 4; ++i) {
      float s = 0.f, sq = 0.f;
#pragma unroll
      for (int ct = 0; ct < 4; ++ct) { s += xreg[ct][i]; sq += xreg[ct][i] * xreg[ct][i]; }
      for (int off = 1; off < 16; off <<= 1) { s += __shfl_xor(s, off); sq += __shfl_xor(sq, off); }
      if (l16 == 0) { red1[wc][rowbase + quad * 4 + i] = s; red2[wc][rowbase + quad * 4 + i] = sq; }
    }
    __syncthreads();                               // #1: red visible
    float mu1[4], rs1[4];
#pragma unroll
    for (int i = 0; i < 4; ++i) {
      int r = rowbase + quad * 4 + i;
      float mu = (red1[0][r] + red1[1][r]) * (1.f / 128.f);
      float var = (red2[0][r] + red2[1][r]) * (1.f / 128.f) - mu * mu;
      mu1[i] = mu;
      rs1[i] = rsqrtf(var + 1e-5f);
    }
#pragma unroll
    for (int ct = 0; ct < 4; ++ct)
#pragma unroll
      for (int i = 0; i < 4; ++i) {
        float h = (xreg[ct][i] - mu1[i]) * rs1[i] * g1v[ct] + b1v[ct];
        As[cwo[ct * 4 + i]] = f2bf(h);
      }
    __syncthreads();                               // #2: As(h); K,V,Q drained

    // ------------- fused K,V MFMA; wave-private store; Q under drain -------
    {
      f32x4 aK[4], aV[4];
#pragma unroll
      for (int i2 = 0; i2 < 4; ++i2) { aK[i2] = f32x4{0.f,0.f,0.f,0.f}; aV[i2] = f32x4{0.f,0.f,0.f,0.f}; }
      mfmaKV(As, Bs[0], Bs[1], aoff, boff, aK, aV);
#pragma unroll
      for (int ct = 0; ct < 4; ++ct)
#pragma unroll
        for (int i = 0; i < 4; ++i) {
          int rowL = rowbase + quad * 4 + i;
          int col = colbase + ct * 16 + l16;
          KVs[rowL * 256 + col] = f2bf(aK[ct][i]);
          KVs[rowL * 256 + 128 + col] = f2bf(aV[ct][i]);
        }
      // readback ONLY this wave's quadrant (16 rows x [colbase..+64) of K,V):
      // intra-wave LDS RAW (compiler waits lgkmcnt); no block sync needed.
      // agent-scope dword atomics write through to L2.
      const size_t grow = (size_t)(row0 + rowbase) * 256;
#pragma unroll
      for (int u = 0; u < 4; ++u) {
        int c = u * 64 + lane;                     // 0..255 chunks of 16 B
        int row = c >> 4, k = c & 15;
        int off = ((k & 8) << 4) + colbase + ((k & 7) << 3);  // K seg / V seg
        uint4 d = *(const uint4*)&KVs[(rowbase + row) * 256 + off];
        unsigned* gp = (unsigned*)(kv + grow + (size_t)row * 256 + off);
        __hip_atomic_store(gp + 0, d.x, __ATOMIC_RELAXED, __HIP_MEMORY_SCOPE_AGENT);
        __hip_atomic_store(gp + 1, d.y, __ATOMIC_RELAXED, __HIP_MEMORY_SCOPE_AGENT);
        __hip_atomic_store(gp + 2, d.z, __ATOMIC_RELAXED, __HIP_MEMORY_SCOPE_AGENT);
        __hip_atomic_store(gp + 3, d.w, __ATOMIC_RELAXED, __HIP_MEMORY_SCOPE_AGENT);
      }
    }
    {  // Q -> Cs (swizzled A-layout); MFMA covers the kv store drain
      f32x4 qacc[4];
#pragma unroll
      for (int i2 = 0; i2 < 4; ++i2) qacc[i2] = f32x4{0.f,0.f,0.f,0.f};
      mfmaS(As, Bs[2], aoff, boff, qacc);
      writeC<false>(Cs, cwo, qacc);
    }

    // -------- per-batch fence-free barrier (XCD-local counter) -------------
    __syncthreads();  // #3: each wave drains its own kv stores before the bump
    issue_tile(wt + 3 * TILE, Bs[0], w, lane);     // Wo lands under the poll
    if (t == 0) {
      __hip_atomic_fetch_add(bcnt, 1u, __ATOMIC_RELAXED, __HIP_MEMORY_SCOPE_AGENT);
      const unsigned target = (unsigned)(BPB * (l + 1));
      while (__hip_atomic_load(bcnt, __ATOMIC_RELAXED, __HIP_MEMORY_SCOPE_AGENT) < target)
        __builtin_amdgcn_s_sleep(1);
    }
    __syncthreads();

    // ------- attention (48 rows x 8 heads, one/thread; chunk-8 gather) -----
    {
      const int rL = t >> 3, h = t & 7;
      const int srow = row0 + rL - bS;
      const int cnt = sCnt[rL];
      float q[16];
      {
        u16x8 qa = *(const u16x8*)&Cs[rL * 128 + (((2 * h) ^ (rL & 15)) << 3)];
        u16x8 qb = *(const u16x8*)&Cs[rL * 128 + (((2 * h + 1) ^ (rL & 15)) << 3)];
#pragma unroll
        for (int jx = 0; jx < 8; ++jx) { q[jx] = bf2f(qa[jx]); q[8 + jx] = bf2f(qb[jx]); }
      }
      float m = -1e30f, lsum = 0.f;
      float o16[16];
#pragma unroll
      for (int jx = 0; jx < 16; ++jx) o16[jx] = 0.f;
      for (int jb = 0; jb < cnt; jb += 8) {        // 8 neighbors in flight
        u16x8 K[8][2], V[8][2];
#pragma unroll
        for (int u = 0; u < 8; ++u) {
          int jj = jb + u;
          int key = 0;
          if (jj < cnt) key = (jj < LKEY) ? sKeys[rL * LKEY + jj] : adj[srow * MAXDEG + jj];
          const u16x8* kp = (const u16x8*)(kv + (size_t)(bS + key) * 256 + h * 16);
          K[u][0] = kp[0];  K[u][1] = kp[1];
          V[u][0] = kp[16]; V[u][1] = kp[17];
        }
        float dot[8];
#pragma unroll
        for (int u = 0; u < 8; ++u) {
          float d = 0.f;
#pragma unroll
          for (int jx = 0; jx < 8; ++jx) {
            d = fmaf(q[jx], bf2f(K[u][0][jx]), d);
            d = fmaf(q[8 + jx], bf2f(K[u][1][jx]), d);
          }
          dot[u] = (jb + u < cnt) ? d * 0.25f : -1e30f;  // 1/sqrt(HD)
        }
        float cm = fmaxf(fmaxf(fmaxf(dot[0], dot[1]), fmaxf(dot[2], dot[3])),
                         fmaxf(fmaxf(dot[4], dot[5]), fmaxf(dot[6], dot[7])));
        float mn = fmaxf(m, cm);
        float rescale = __expf(m - mn);              // one rescale per chunk
        lsum *= rescale;
#pragma unroll
        for (int jx = 0; jx < 16; ++jx) o16[jx] *= rescale;
#pragma unroll
        for (int u = 0; u < 8; ++u) {
          float e = __expf(dot[u] - mn);
          lsum += e;
#pragma unroll
          for (int jx = 0; jx < 8; ++jx) {
            o16[jx]     = fmaf(e, bf2f(V[u][0][jx]), o16[jx]);
            o16[8 + jx] = fmaf(e, bf2f(V[u][1][jx]), o16[8 + jx]);
          }
        }
        m = mn;
      }
      const float inv = 1.f / lsum;
      u16x8 pk0, pk1;
#pragma unroll
      for (int jx = 0; jx < 8; ++jx) {
        pk0[jx] = f2bf(o16[jx] * inv);
        pk1[jx] = f2bf(o16[8 + jx] * inv);
      }
      *(u16x8*)&As[rL * 128 + (((2 * h) ^ (rL & 15)) << 3)] = pk0;
      *(u16x8*)&As[rL * 128 + (((2 * h + 1) ^ (rL & 15)) << 3)] = pk1;
    }
    __syncthreads();                               // #4: As(o); Wo drained
    issue_tile(wt + 4 * TILE, Bs[1], w, lane);     // W1c0 (V slot free)
    issue_tile(wt + 5 * TILE, Bs[2], w, lane);     // W2c0 (Q slot free)

    // ---------------- Wo; x'; LN2*te -> As ---------------------------------
    f32x4 acc1[4];
#pragma unroll
    for (int i2 = 0; i2 < 4; ++i2) acc1[i2] = f32x4{0.f, 0.f, 0.f, 0.f};
    mfmaS(As, Bs[0], aoff, boff, acc1);
    f32x4 xp[4];
#pragma unroll
    for (int ct = 0; ct < 4; ++ct)
#pragma unroll
      for (int i = 0; i < 4; ++i) xp[ct][i] = xreg[ct][i] + acc1[ct][i];
#pragma unroll
    for (int i = 0; i < 4; ++i) {
      float s = 0.f, sq = 0.f;
#pragma unroll
      for (int ct = 0; ct < 4; ++ct) { s += xp[ct][i]; sq += xp[ct][i] * xp[ct][i]; }
      for (int off = 1; off < 16; off <<= 1) { s += __shfl_xor(s, off); sq += __shfl_xor(sq, off); }
      if (l16 == 0) { red1[wc][rowbase + quad * 4 + i] = s; red2[wc][rowbase + quad * 4 + i] = sq; }
    }
    __syncthreads();                               // #5: red; all Wo As-reads done
    float mu2[4], rs2[4];
#pragma unroll
    for (int i = 0; i < 4; ++i) {
      int r = rowbase + quad * 4 + i;
      float mu = (red1[0][r] + red1[1][r]) * (1.f / 128.f);
      float var = (red2[0][r] + red2[1][r]) * (1.f / 128.f) - mu * mu;
      mu2[i] = mu;
      rs2[i] = rsqrtf(var + 1e-5f);
    }
#pragma unroll
    for (int ct = 0; ct < 4; ++ct)
#pragma unroll
      for (int i = 0; i < 4; ++i) {
        float h2 = (xp[ct][i] - mu2[i]) * rs2[i] * g2v[ct] + b2v[ct];
        h2 *= teR[ct];
        As[cwo[ct * 4 + i]] = f2bf(h2);
      }
    __syncthreads();                               // #6: As(h2); W1c0,W2c0 drained

    // ---------------- FFN: ring-scheduled stages (2 syncs/chunk) -----------
    // buffer ring: c0 W1@1 W2@2; c1 W1@0 W2@1; c2 W1@2 W2@0; c3 W1@1 W2@2.
    // Every issue->use crosses exactly one barrier (W1(c+1): issued at c
    // sync1, used after c sync2; W2(c+1): issued at c sync2, used after
    // c+1 sync1). Buffer-free-at-issue also holds on every edge.
    f32x4 acc2[4];
#pragma unroll
    for (int i2 = 0; i2 < 4; ++i2) acc2[i2] = f32x4{0.f, 0.f, 0.f, 0.f};
#pragma unroll
    for (int c = 0; c < 4; ++c) {
      f32x4 accF[4];
#pragma unroll
      for (int i2 = 0; i2 < 4; ++i2) accF[i2] = f32x4{0.f, 0.f, 0.f, 0.f};
      mfmaS(As, Bs[bufW1[c]], aoff, boff, accF);
      writeC<true>(Cs, cwo, accF);
      __syncthreads();  // hf visible; W1c reads done; prior issues drained
      if (c < 3) issue_tile(wt + (size_t)(4 + 2 * (c + 1)) * TILE, Bs[bufW1[c + 1]], w, lane);
      else if (l < L_ - 1) issue_tile(wt + WLAYER + 0 * TILE, Bs[0], w, lane);  // next K
      mfmaS(Cs, Bs[bufW2[c]], aoff, boff, acc2);
      __syncthreads();  // Cs reads done (safe rewrite); W2c reads done
      if (c < 3) issue_tile(wt + (size_t)(5 + 2 * (c + 1)) * TILE, Bs[bufW2[c + 1]], w, lane);
      else if (l < L_ - 1) {
        issue_tile(wt + WLAYER + 1 * TILE, Bs[1], w, lane);  // next V
        issue_tile(wt + WLAYER + 2 * TILE, Bs[2], w, lane);  // next Q
      }
    }
    // epilogue: x'' = x' + ffn (registers only)
    if (l < L_ - 1) {
#pragma unroll
      for (int ct = 0; ct < 4; ++ct)
#pragma unroll
        for (int i = 0; i < 4; ++i) xreg[ct][i] = xp[ct][i] + acc2[ct][i];
    } else {
      float pr[4] = {0.f, 0.f, 0.f, 0.f};
#pragma unroll
      for (int ct = 0; ct < 4; ++ct)
#pragma unroll
        for (int i = 0; i < 4; ++i)
          pr[i] += (xp[ct][i] + acc2[ct][i]) * fcw[colbase + ct * 16 + l16];
#pragma unroll
      for (int i = 0; i < 4; ++i) {
        float s = pr[i];
        for (int off = 1; off < 16; off <<= 1) s += __shfl_xor(s, off);
        if (l16 == 0) red1[wc][rowbase + quad * 4 + i] = s;
      }
      __syncthreads();
      if (wc == 0 && l16 == 0)
#pragma unroll
        for (int i = 0; i < 4; ++i) {
          int r = rowbase + quad * 4 + i;
          out[row0 + r] = red1[0][r] + red1[1][r] + fcb[0];
        }
    }
  }
}

// ---------------------------------------------------------------------------
extern "C" void kernel_launch(void* const* d_in, const int* in_sizes, int n_in,
                              void* d_out, int out_size, void* d_ws, size_t ws_size,
                              hipStream_t stream) {
  const float* r_t       = (const float*)d_in[0];
  const int*   t         = (const int*)d_in[1];
  const int*   pcm       = (const int*)d_in[2];
  const float* src_embed = (const float*)d_in[4];
  const float* time_tab  = (const float*)d_in[5];
  const float* Wq = (const float*)d_in[6];
  const float* Wk = (const float*)d_in[7];
  const float* Wv = (const float*)d_in[8];
  const float* Wo = (const float*)d_in[9];
  const float* W1 = (const float*)d_in[10];
  const float* W2 = (const float*)d_in[11];
  const float* g1 = (const float*)d_in[12];
  const float* b1 = (const float*)d_in[13];
  const float* g2 = (const float*)d_in[14];
  const float* b2 = (const float*)d_in[15];
  const float* fc_w = (const float*)d_in[16];
  const float* fc_b = (const float*)d_in[17];
  float* out = (float*)d_out;

  char* ws = (char*)d_ws;
  size_t off = 0;
  auto alloc = [&](size_t bytes) -> void* {
    void* p = ws + off;
    off = (off + bytes + 255) & ~(size_t)255;
    return p;
  };
  unsigned short* kv   = (unsigned short*)alloc((size_t)L_ * KVSZ * 2);  // per-layer
  int*            adj  = (int*)alloc((size_t)S_ * MAXDEG * 4);
  // adjcnt + bcnt contiguous -> one memset clears both
  int*            adjc = (int*)alloc((size_t)S_ * 4 + 8 * 32 * 4);
  unsigned*       bcnt = (unsigned*)(adjc + S_);
  unsigned short* wbf  = (unsigned short*)alloc((size_t)L_ * WLAYER * 2);

  hipMemsetAsync(adjc, 0, (size_t)S_ * 4 + 8 * 32 * 4, stream);
  setup_kernel<<<WBLK + ABLK, 256, 0, stream>>>(Wq, Wk, Wv, Wo, W1, W2, wbf,
                                                pcm, adj, adjc);
  mega_kernel<<<NBLK, 384, 0, stream>>>(r_t, src_embed, kv, wbf, g1, b1, g2, b2,
                                        t, time_tab, adj, adjc, fc_w, fc_b, out, bcnt);
}

// Round 17
// 258.758 us; speedup vs baseline: 1.0922x; 1.0922x over previous
//
#include <hip/hip_runtime.h>
#include <cmath>
#include <cstdint>

// Problem constants (from reference)
constexpr int B_ = 8, N_ = 1024, M_ = 512, D_ = 128, S_ = 1536, L_ = 6, DFF_ = 512;
constexpr int ROWS = B_ * S_;    // 12288
constexpr int MAXDEG = 64;       // max attention row degree (actual ~4-25)
constexpr int LKEY = 32;         // LDS-cached keys per row
constexpr int RPB  = 48;         // rows per block
constexpr int NBLK = ROWS / RPB; // 256 persistent blocks (1/CU, all resident)
constexpr int BPB  = S_ / RPB;   // 32 blocks per batch (barrier group)
constexpr int NTILE = 12;        // weight tiles per layer, in stage order
constexpr int TILE  = 128 * 128; // halfwords per tile (LDS image, 32 KB)
constexpr int KVSZ  = ROWS * 256;// halfwords per kv layer-buffer
constexpr int WBLK  = L_ * NTILE * 2;  // 144 wconv half-tile blocks
constexpr int ABLK  = 128;             // adj blocks (4 check rows each)
constexpr int WLAYER = NTILE * TILE;   // 196608 halfwords per layer

typedef __bf16 bf16x8 __attribute__((ext_vector_type(8)));
typedef float  f32x4  __attribute__((ext_vector_type(4)));
typedef unsigned short u16x8 __attribute__((ext_vector_type(8)));

__device__ inline unsigned short f2bf(float f) {  // native hw RNE convert
  return __builtin_bit_cast(unsigned short, (__bf16)f);
}
__device__ inline float bf2f(unsigned short u) {
  return __uint_as_float(((unsigned)u) << 16);
}

// Direct global->LDS async copy, 16 B/lane (m97's lever).
__device__ __forceinline__ void async_ld16(const unsigned short* g, unsigned short* l) {
  __builtin_amdgcn_global_load_lds(
      (const __attribute__((address_space(1))) unsigned int*)(uintptr_t)g,
      (__attribute__((address_space(3))) unsigned int*)(unsigned)(uintptr_t)l,
      16, 0, 0);
}
// Issue one 32 KB tile (pre-swizzled LDS image) into a Bs buffer.
// NOTE: tile is split across all 6 waves -> every issue->use path MUST have
// >=1 __syncthreads between them (only a barrier drains other waves' vmcnt).
__device__ __forceinline__ void issue_tile(const unsigned short* tp, unsigned short* bs,
                                           int w, int lane) {
  for (int c = w; c < 32; c += 6)
    async_ld16(tp + c * 512 + lane * 8, bs + c * 512);
}

// ---------------------------------------------------------------------------
// Combined setup kernel (adjcnt/bcnt pre-zeroed via hipMemsetAsync):
//  blocks [0, WBLK): weight convert, one 64-kd half-tile each, via LDS
//    transpose staging. Tile/stage order: [0]=Wk^T [1]=Wv^T [2]=Wq^T [3]=Wo^T
//    [4+2c]=W1^T chunk c [5+2c]=W2^T chunk c.
//    Image: tile[rr*128 + ((cc^(rr&15))<<3) + e] = W^T[rr][cc*8+e].
//  blocks [WBLK, WBLK+ABLK): adjacency from pcm ROWS, both Tanner directions
//    + self-edges via atomic append (order irrelevant: softmax and mod-2
//    syndrome are permutation-invariant).
// ---------------------------------------------------------------------------
__global__ void setup_kernel(const float* __restrict__ Wq, const float* __restrict__ Wk,
                             const float* __restrict__ Wv, const float* __restrict__ Wo,
                             const float* __restrict__ W1, const float* __restrict__ W2,
                             unsigned short* __restrict__ out, const int* __restrict__ pcm,
                             int* __restrict__ adj, int* __restrict__ adjcnt) {
  int bid = blockIdx.x;
  if (bid >= WBLK) {  // ---- adjacency blocks: 4 check rows + 12 self-rows ----
    int ab = bid - WBLK;
    int c0 = ab * 4, lane = threadIdx.x & 63, sub = threadIdx.x >> 6;  // 4 subrows
    if (threadIdx.x < 12) {
      int s = ab * 12 + threadIdx.x;
      int slot = atomicAdd(&adjcnt[s], 1);
      if (slot < MAXDEG) adj[s * MAXDEG + slot] = s;
    }
    int c = c0 + sub;
    const int* row = pcm + c * N_;
    for (int base = 0; base < N_; base += 64) {
      int k = base + lane;
      if (row[k] != 0) {
        int s1 = atomicAdd(&adjcnt[N_ + c], 1);
        if (s1 < MAXDEG) adj[(N_ + c) * MAXDEG + s1] = k;
        int s2 = atomicAdd(&adjcnt[k], 1);
        if (s2 < MAXDEG) adj[k * MAXDEG + s2] = N_ + c;
      }
    }
    return;
  }
  // ---- weight-convert blocks ----
  __shared__ unsigned short tl[64 * 130];  // +2 pad breaks transpose conflicts
  int tb = bid >> 1, half = bid & 1;
  int l = tb / NTILE, tile = tb % NTILE;
  const int kd0 = half * 64;
  const float* src;
  int rstride, coff = 0;
  if (tile == 0)      { src = Wk + (size_t)l * D_ * D_;  rstride = D_; }
  else if (tile == 1) { src = Wv + (size_t)l * D_ * D_;  rstride = D_; }
  else if (tile == 2) { src = Wq + (size_t)l * D_ * D_;  rstride = D_; }
  else if (tile == 3) { src = Wo + (size_t)l * D_ * D_;  rstride = D_; }
  else {
    int c = (tile - 4) >> 1;
    if (((tile - 4) & 1) == 0) { src = W1 + (size_t)l * D_ * DFF_; rstride = DFF_; coff = c * 128; }
    else                       { src = W2 + (size_t)l * DFF_ * D_ + (size_t)c * 128 * D_; rstride = D_; }
  }
  for (int i = threadIdx.x; i < 8192; i += 256) {
    int kd = i >> 7, rr = i & 127;
    tl[kd * 130 + rr] = f2bf(src[(size_t)(kd0 + kd) * rstride + coff + rr]);
  }
  __syncthreads();
  unsigned short* o = out + (size_t)tb * TILE;
  for (int i = threadIdx.x; i < 8192; i += 256) {
    int rr = i >> 6;
    int kloc = i & 63;
    int kd = kd0 + kloc;
    int cc = kd >> 3, e = kd & 7;
    int sw = cc ^ (rr & 15);
    o[rr * 128 + (sw << 3) + e] = tl[kloc * 130 + rr];
  }
}

// ---------------------------------------------------------------------------
// MFMA helpers, precomputed halfword offsets (swizzle derived once/thread).
// Wave tile = 16 rows x 64 cols (4 tiles of 16x16), K=128 in 4 steps of 32.
// ---------------------------------------------------------------------------
__device__ __forceinline__ void mfmaS(const unsigned short* A, const unsigned short* Bt,
                                      const int (&ao)[4], const int (&bo)[16],
                                      f32x4 (&acc)[4]) {
#pragma unroll
  for (int kk = 0; kk < 4; ++kk) {
    bf16x8 a = __builtin_bit_cast(bf16x8, *(const uint4*)&A[ao[kk]]);
#pragma unroll
    for (int ct = 0; ct < 4; ++ct) {
      bf16x8 bb = __builtin_bit_cast(bf16x8, *(const uint4*)&Bt[bo[kk * 4 + ct]]);
      acc[ct] = __builtin_amdgcn_mfma_f32_16x16x32_bf16(a, bb, acc[ct], 0, 0, 0);
    }
  }
}
// Fused K+V stage: each A-fragment read once, feeds both B tiles.
__device__ __forceinline__ void mfmaKV(const unsigned short* A, const unsigned short* Kt,
                                       const unsigned short* Vt, const int (&ao)[4],
                                       const int (&bo)[16], f32x4 (&aK)[4], f32x4 (&aV)[4]) {
#pragma unroll
  for (int kk = 0; kk < 4; ++kk) {
    bf16x8 a = __builtin_bit_cast(bf16x8, *(const uint4*)&A[ao[kk]]);
#pragma unroll
    for (int ct = 0; ct < 4; ++ct) {
      bf16x8 bk = __builtin_bit_cast(bf16x8, *(const uint4*)&Kt[bo[kk * 4 + ct]]);
      bf16x8 bv = __builtin_bit_cast(bf16x8, *(const uint4*)&Vt[bo[kk * 4 + ct]]);
      aK[ct] = __builtin_amdgcn_mfma_f32_16x16x32_bf16(a, bk, aK[ct], 0, 0, 0);
      aV[ct] = __builtin_amdgcn_mfma_f32_16x16x32_bf16(a, bv, aV[ct], 0, 0, 0);
    }
  }
}
template <bool RELU>
__device__ __forceinline__ void writeC(unsigned short* base, const int (&co)[16],
                                       const f32x4 (&acc)[4]) {
#pragma unroll
  for (int ct = 0; ct < 4; ++ct)
#pragma unroll
    for (int i = 0; i < 4; ++i) {
      float v = acc[ct][i];
      if constexpr (RELU) v = fmaxf(v, 0.f);
      base[co[ct * 4 + i]] = f2bf(v);
    }
}

// ---------------------------------------------------------------------------
// Persistent mega-kernel: x-init + all 6 layers + fc head.
// grid = 256 blocks x 384 thr (6 waves); block owns 48 rows; 1 block/CU.
// XCD affinity: batch = blockIdx%8 (as in the last passing round-3 config).
// KV path: R0-PROVEN structure — fused K+V MFMA -> KVs; __syncthreads (KVs
// visible block-wide); block-wide dense dword store loop (WRITE_SIZE-exact:
// 64 consecutive lanes per instruction cover a 256B run); Q MFMA issued
// after the stores so the store drain hides under it; then the per-batch
// fence-free barrier. (Two wave-private readback variants raced — reverted.)
// FFN: proven 2-sync ring (every issue->use crosses >=1 barrier).
// LDS: As 12K + Bs 96K + Cs 12K + KVs 24K + red/keys ~8K ~= 152 KB.
// ---------------------------------------------------------------------------
__global__ void __launch_bounds__(384) mega_kernel(
    const float* __restrict__ r_t, const float* __restrict__ se,
    unsigned short* __restrict__ kvbase, const unsigned short* __restrict__ wbf,
    const float* __restrict__ g1, const float* __restrict__ b1,
    const float* __restrict__ g2, const float* __restrict__ b2,
    const int* __restrict__ tt, const float* __restrict__ table,
    const int* __restrict__ adj, const int* __restrict__ adjc,
    const float* __restrict__ fcw, const float* __restrict__ fcb,
    float* __restrict__ out, unsigned* barrier_cnt) {
  __shared__ unsigned short As[RPB * 128];      // 12 KB
  __shared__ unsigned short Bs[3][TILE];        // 96 KB (ring)
  __shared__ unsigned short Cs[RPB * 128];      // 12 KB (Q, then FFN hf)
  __shared__ unsigned short KVs[RPB * 256];     // 24 KB (K|V repack)
  __shared__ float red1[2][RPB], red2[2][RPB];
  __shared__ float nodeS[RPB];
  __shared__ int sKeys[RPB * LKEY];             // 6 KB
  __shared__ int sCnt[RPB];
  const int b = blockIdx.x & 7;                 // batch -> XCD (round-3 passing map)
  const int jblk = blockIdx.x >> 3;             // 0..31 within batch
  const int row0 = b * S_ + jblk * RPB;
  const int bS = b * S_;
  const int t = threadIdx.x, w = t >> 6, lane = t & 63, quad = lane >> 4, l16 = lane & 15;
  const int wr = w >> 1, wc = w & 1;
  const int rowbase = wr * 16, colbase = wc * 64;
  const int tbase = tt[b] * D_;
  unsigned* bcnt = barrier_cnt + b * 32;        // per-batch counter, 128 B apart

  // ---- precomputed swizzled LDS fragment offsets (halfwords) --------------
  int aoff[4], boff[16], cwo[16];
#pragma unroll
  for (int kk = 0; kk < 4; ++kk) {
    int row = rowbase + l16, cb = kk * 4 + quad;
    aoff[kk] = row * 128 + ((cb ^ (row & 15)) << 3);
#pragma unroll
    for (int ct = 0; ct < 4; ++ct) {
      int n = colbase + ct * 16 + l16;
      boff[kk * 4 + ct] = n * 128 + ((cb ^ (n & 15)) << 3);
    }
  }
#pragma unroll
  for (int ct = 0; ct < 4; ++ct)
#pragma unroll
    for (int i = 0; i < 4; ++i) {
      int rowL = rowbase + quad * 4 + i, col = colbase + ct * 16 + l16;
      cwo[ct * 4 + i] = rowL * 128 + (((col >> 3) ^ (rowL & 15)) << 3) + (col & 7);
    }
  float teR[4];
#pragma unroll
  for (int ct = 0; ct < 4; ++ct) teR[ct] = table[tbase + colbase + ct * 16 + l16];

  // prime the pipeline: layer-0 K,V,Q tiles -> Bs[0..2]
  issue_tile(wbf + 0 * TILE, Bs[0], w, lane);
  issue_tile(wbf + 1 * TILE, Bs[1], w, lane);
  issue_tile(wbf + 2 * TILE, Bs[2], w, lane);

  // ---- prologue: adjacency cache, node values (8 thr/row), x -> registers -
  if (t < RPB) {
    int c = adjc[row0 + t - bS];
    sCnt[t] = c < MAXDEG ? c : MAXDEG;
  }
  for (int i = t; i < RPB * LKEY; i += 384) {
    int r = i / LKEY, j = i % LKEY;
    sKeys[i] = adj[(row0 + r - bS) * MAXDEG + j];  // tail values unused
  }
  __syncthreads();
  {  // task = (row rL, slot p): 48 x 8 = 384
    const int rL = t >> 3, p = t & 7;
    const int s = row0 + rL - bS;
    float node;
    if (s < N_) {
      node = fabsf(r_t[b * N_ + s]);
    } else {
      const int cnt = sCnt[rL];
      float sum = 0.f;
      for (int j = p; j < cnt; j += 8) {
        int k = (j < LKEY) ? sKeys[rL * LKEY + j] : adj[s * MAXDEG + j];
        if (k < N_) {
          float r = r_t[b * N_ + k];
          sum += (r < 0.f) ? 1.f : (r > 0.f ? 0.f : 0.5f);  // bits = 0.5*(1-sign)
        }
      }
      sum += __shfl_xor(sum, 1, 16);
      sum += __shfl_xor(sum, 2, 16);
      sum += __shfl_xor(sum, 4, 16);
      node = fmodf(sum, 2.0f);
    }
    if (p == 0) nodeS[rL] = node;
  }
  __syncthreads();
  // persistent x in registers (MFMA C-layout): x = te * se * node
  f32x4 xreg[4];
#pragma unroll
  for (int ct = 0; ct < 4; ++ct)
#pragma unroll
    for (int i = 0; i < 4; ++i) {
      int rowL = rowbase + quad * 4 + i;
      int s = row0 + rowL - bS;
      int col = colbase + ct * 16 + l16;
      xreg[ct][i] = teR[ct] * se[(size_t)s * D_ + col] * nodeS[rowL];
    }

  constexpr int bufW1[4] = {1, 0, 2, 1};
  constexpr int bufW2[4] = {2, 1, 0, 2};

  for (int l = 0; l < L_; ++l) {
    const unsigned short* wt = wbf + (size_t)l * WLAYER;
    unsigned short* kv = kvbase + (size_t)l * KVSZ;
    const float* g1l = g1 + l * D_;
    const float* b1l = b1 + l * D_;
    const float* g2l = g2 + l * D_;
    const float* b2l = b2 + l * D_;
    float g1v[4], b1v[4], g2v[4], b2v[4];
#pragma unroll
    for (int ct = 0; ct < 4; ++ct) {
      int col = colbase + ct * 16 + l16;
      g1v[ct] = g1l[col]; b1v[ct] = b1l[col];
      g2v[ct] = g2l[col]; b2v[ct] = b2l[col];
    }

    // ------------- LN1 (one-pass var) on register x -> bf16 h in As --------
#pragma unroll
    for (int i = 0; i < 4; ++i) {
      float s = 0.f, sq = 0.f;
#pragma unroll
      for (int ct = 0; ct < 4; ++ct) { s += xreg[ct][i]; sq += xreg[ct][i] * xreg[ct][i]; }
      for (int off = 1; off < 16; off <<= 1) { s += __shfl_xor(s, off); sq += __shfl_xor(sq, off); }
      if (l16 == 0) { red1[wc][rowbase + quad * 4 + i] = s; red2[wc][rowbase + quad * 4 + i] = sq; }
    }
    __syncthreads();                               // #1: red visible
    float mu1[4], rs1[4];
#pragma unroll
    for (int i = 0; i < 4; ++i) {
      int r = rowbase + quad * 4 + i;
      float mu = (red1[0][r] + red1[1][r]) * (1.f / 128.f);
      float var = (red2[0][r] + red2[1][r]) * (1.f / 128.f) - mu * mu;
      mu1[i] = mu;
      rs1[i] = rsqrtf(var + 1e-5f);
    }
#pragma unroll
    for (int ct = 0; ct < 4; ++ct)
#pragma unroll
      for (int i = 0; i < 4; ++i) {
        float h = (xreg[ct][i] - mu1[i]) * rs1[i] * g1v[ct] + b1v[ct];
        As[cwo[ct * 4 + i]] = f2bf(h);
      }
    __syncthreads();                               // #2: As(h); K,V,Q drained

    // ------------- fused K,V MFMA -> KVs -----------------------------------
    {
      f32x4 aK[4], aV[4];
#pragma unroll
      for (int i2 = 0; i2 < 4; ++i2) { aK[i2] = f32x4{0.f,0.f,0.f,0.f}; aV[i2] = f32x4{0.f,0.f,0.f,0.f}; }
      mfmaKV(As, Bs[0], Bs[1], aoff, boff, aK, aV);
#pragma unroll
      for (int ct = 0; ct < 4; ++ct)
#pragma unroll
        for (int i = 0; i < 4; ++i) {
          int rowL = rowbase + quad * 4 + i;
          int col = colbase + ct * 16 + l16;
          KVs[rowL * 256 + col] = f2bf(aK[ct][i]);
          KVs[rowL * 256 + 128 + col] = f2bf(aV[ct][i]);
        }
    }
    __syncthreads();                               // #3: KVs complete block-wide
    // R0-proven block-wide dense kv store: 128 dwords/row, 64 consecutive
    // lanes per instruction -> 256B contiguous runs, write-through exact.
    for (int i = t; i < RPB * 128; i += 384) {
      int rL = i >> 7, cw = i & 127;
      unsigned u = *(const unsigned*)&KVs[rL * 256 + cw * 2];
      __hip_atomic_store((unsigned*)&kv[(size_t)(row0 + rL) * 256 + cw * 2],
                         u, __ATOMIC_RELAXED, __HIP_MEMORY_SCOPE_AGENT);
    }
    {  // Q -> Cs (swizzled A-layout); MFMA covers the kv store drain
      f32x4 qacc[4];
#pragma unroll
      for (int i2 = 0; i2 < 4; ++i2) qacc[i2] = f32x4{0.f,0.f,0.f,0.f};
      mfmaS(As, Bs[2], aoff, boff, qacc);
      writeC<false>(Cs, cwo, qacc);
    }

    // -------- per-batch fence-free barrier ---------------------------------
    __syncthreads();  // #4: drains every wave's kv stores before the bump
    issue_tile(wt + 3 * TILE, Bs[0], w, lane);     // Wo lands under the poll
    if (t == 0) {
      __hip_atomic_fetch_add(bcnt, 1u, __ATOMIC_RELAXED, __HIP_MEMORY_SCOPE_AGENT);
      const unsigned target = (unsigned)(BPB * (l + 1));
      while (__hip_atomic_load(bcnt, __ATOMIC_RELAXED, __HIP_MEMORY_SCOPE_AGENT) < target)
        __builtin_amdgcn_s_sleep(1);
    }
    __syncthreads();                               // #5: barrier done

    // ------- attention (48 rows x 8 heads, one/thread; chunk-8 gather) -----
    {
      const int rL = t >> 3, h = t & 7;
      const int srow = row0 + rL - bS;
      const int cnt = sCnt[rL];
      float q[16];
      {
        u16x8 qa = *(const u16x8*)&Cs[rL * 128 + (((2 * h) ^ (rL & 15)) << 3)];
        u16x8 qb = *(const u16x8*)&Cs[rL * 128 + (((2 * h + 1) ^ (rL & 15)) << 3)];
#pragma unroll
        for (int jx = 0; jx < 8; ++jx) { q[jx] = bf2f(qa[jx]); q[8 + jx] = bf2f(qb[jx]); }
      }
      float m = -1e30f, lsum = 0.f;
      float o16[16];
#pragma unroll
      for (int jx = 0; jx < 16; ++jx) o16[jx] = 0.f;
      for (int jb = 0; jb < cnt; jb += 8) {        // 8 neighbors in flight
        u16x8 K[8][2], V[8][2];
#pragma unroll
        for (int u = 0; u < 8; ++u) {
          int jj = jb + u;
          int key = 0;
          if (jj < cnt) key = (jj < LKEY) ? sKeys[rL * LKEY + jj] : adj[srow * MAXDEG + jj];
          const u16x8* kp = (const u16x8*)(kv + (size_t)(bS + key) * 256 + h * 16);
          K[u][0] = kp[0];  K[u][1] = kp[1];
          V[u][0] = kp[16]; V[u][1] = kp[17];
        }
        float dot[8];
#pragma unroll
        for (int u = 0; u < 8; ++u) {
          float d = 0.f;
#pragma unroll
          for (int jx = 0; jx < 8; ++jx) {
            d = fmaf(q[jx], bf2f(K[u][0][jx]), d);
            d = fmaf(q[8 + jx], bf2f(K[u][1][jx]), d);
          }
          dot[u] = (jb + u < cnt) ? d * 0.25f : -1e30f;  // 1/sqrt(HD)
        }
        float cm = fmaxf(fmaxf(fmaxf(dot[0], dot[1]), fmaxf(dot[2], dot[3])),
                         fmaxf(fmaxf(dot[4], dot[5]), fmaxf(dot[6], dot[7])));
        float mn = fmaxf(m, cm);
        float rescale = __expf(m - mn);              // one rescale per chunk
        lsum *= rescale;
#pragma unroll
        for (int jx = 0; jx < 16; ++jx) o16[jx] *= rescale;
#pragma unroll
        for (int u = 0; u < 8; ++u) {
          float e = __expf(dot[u] - mn);
          lsum += e;
#pragma unroll
          for (int jx = 0; jx < 8; ++jx) {
            o16[jx]     = fmaf(e, bf2f(V[u][0][jx]), o16[jx]);
            o16[8 + jx] = fmaf(e, bf2f(V[u][1][jx]), o16[8 + jx]);
          }
        }
        m = mn;
      }
      const float inv = 1.f / lsum;
      u16x8 pk0, pk1;
#pragma unroll
      for (int jx = 0; jx < 8; ++jx) {
        pk0[jx] = f2bf(o16[jx] * inv);
        pk1[jx] = f2bf(o16[8 + jx] * inv);
      }
      *(u16x8*)&As[rL * 128 + (((2 * h) ^ (rL & 15)) << 3)] = pk0;
      *(u16x8*)&As[rL * 128 + (((2 * h + 1) ^ (rL & 15)) << 3)] = pk1;
    }
    __syncthreads();                               // #6: As(o); Wo drained
    issue_tile(wt + 4 * TILE, Bs[1], w, lane);     // W1c0 (V slot free)
    issue_tile(wt + 5 * TILE, Bs[2], w, lane);     // W2c0 (Q slot free)

    // ---------------- Wo; x'; LN2*te -> As ---------------------------------
    f32x4 acc1[4];
#pragma unroll
    for (int i2 = 0; i2 < 4; ++i2) acc1[i2] = f32x4{0.f, 0.f, 0.f, 0.f};
    mfmaS(As, Bs[0], aoff, boff, acc1);
    f32x4 xp[4];
#pragma unroll
    for (int ct = 0; ct < 4; ++ct)
#pragma unroll
      for (int i = 0; i < 4; ++i) xp[ct][i] = xreg[ct][i] + acc1[ct][i];
#pragma unroll
    for (int i = 0; i < 4; ++i) {
      float s = 0.f, sq = 0.f;
#pragma unroll
      for (int ct = 0; ct < 4; ++ct) { s += xp[ct][i]; sq += xp[ct][i] * xp[ct][i]; }
      for (int off = 1; off < 16; off <<= 1) { s += __shfl_xor(s, off); sq += __shfl_xor(sq, off); }
      if (l16 == 0) { red1[wc][rowbase + quad * 4 + i] = s; red2[wc][rowbase + quad * 4 + i] = sq; }
    }
    __syncthreads();                               // #7: red; all Wo As-reads done
    float mu2[4], rs2[4];
#pragma unroll
    for (int i = 0; i < 4; ++i) {
      int r = rowbase + quad * 4 + i;
      float mu = (red1[0][r] + red1[1][r]) * (1.f / 128.f);
      float var = (red2[0][r] + red2[1][r]) * (1.f / 128.f) - mu * mu;
      mu2[i] = mu;
      rs2[i] = rsqrtf(var + 1e-5f);
    }
#pragma unroll
    for (int ct = 0; ct < 4; ++ct)
#pragma unroll
      for (int i = 0; i < 4; ++i) {
        float h2 = (xp[ct][i] - mu2[i]) * rs2[i] * g2v[ct] + b2v[ct];
        h2 *= teR[ct];
        As[cwo[ct * 4 + i]] = f2bf(h2);
      }
    __syncthreads();                               // #8: As(h2); W1c0,W2c0 drained

    // ---------------- FFN: ring-scheduled stages (2 syncs/chunk) -----------
    // buffer ring: c0 W1@1 W2@2; c1 W1@0 W2@1; c2 W1@2 W2@0; c3 W1@1 W2@2.
    // Every issue->use crosses exactly one barrier (W1(c+1): issued at c
    // sync1, used after c sync2; W2(c+1): issued at c sync2, used after
    // c+1 sync1). Buffer-free-at-issue also holds on every edge.
    f32x4 acc2[4];
#pragma unroll
    for (int i2 = 0; i2 < 4; ++i2) acc2[i2] = f32x4{0.f, 0.f, 0.f, 0.f};
#pragma unroll
    for (int c = 0; c < 4; ++c) {
      f32x4 accF[4];
#pragma unroll
      for (int i2 = 0; i2 < 4; ++i2) accF[i2] = f32x4{0.f, 0.f, 0.f, 0.f};
      mfmaS(As, Bs[bufW1[c]], aoff, boff, accF);
      writeC<true>(Cs, cwo, accF);
      __syncthreads();  // hf visible; W1c reads done; prior issues drained
      if (c < 3) issue_tile(wt + (size_t)(4 + 2 * (c + 1)) * TILE, Bs[bufW1[c + 1]], w, lane);
      else if (l < L_ - 1) issue_tile(wt + WLAYER + 0 * TILE, Bs[0], w, lane);  // next K
      mfmaS(Cs, Bs[bufW2[c]], aoff, boff, acc2);
      __syncthreads();  // Cs reads done (safe rewrite); W2c reads done
      if (c < 3) issue_tile(wt + (size_t)(5 + 2 * (c + 1)) * TILE, Bs[bufW2[c + 1]], w, lane);
      else if (l < L_ - 1) {
        issue_tile(wt + WLAYER + 1 * TILE, Bs[1], w, lane);  // next V
        issue_tile(wt + WLAYER + 2 * TILE, Bs[2], w, lane);  // next Q
      }
    }
    // epilogue: x'' = x' + ffn (registers only)
    if (l < L_ - 1) {
#pragma unroll
      for (int ct = 0; ct < 4; ++ct)
#pragma unroll
        for (int i = 0; i < 4; ++i) xreg[ct][i] = xp[ct][i] + acc2[ct][i];
    } else {
      float pr[4] = {0.f, 0.f, 0.f, 0.f};
#pragma unroll
      for (int ct = 0; ct < 4; ++ct)
#pragma unroll
        for (int i = 0; i < 4; ++i)
          pr[i] += (xp[ct][i] + acc2[ct][i]) * fcw[colbase + ct * 16 + l16];
#pragma unroll
      for (int i = 0; i < 4; ++i) {
        float s = pr[i];
        for (int off = 1; off < 16; off <<= 1) s += __shfl_xor(s, off);
        if (l16 == 0) red1[wc][rowbase + quad * 4 + i] = s;
      }
      __syncthreads();
      if (wc == 0 && l16 == 0)
#pragma unroll
        for (int i = 0; i < 4; ++i) {
          int r = rowbase + quad * 4 + i;
          out[row0 + r] = red1[0][r] + red1[1][r] + fcb[0];
        }
    }
  }
}

// ---------------------------------------------------------------------------
extern "C" void kernel_launch(void* const* d_in, const int* in_sizes, int n_in,
                              void* d_out, int out_size, void* d_ws, size_t ws_size,
                              hipStream_t stream) {
  const float* r_t       = (const float*)d_in[0];
  const int*   t         = (const int*)d_in[1];
  const int*   pcm       = (const int*)d_in[2];
  const float* src_embed = (const float*)d_in[4];
  const float* time_tab  = (const float*)d_in[5];
  const float* Wq = (const float*)d_in[6];
  const float* Wk = (const float*)d_in[7];
  const float* Wv = (const float*)d_in[8];
  const float* Wo = (const float*)d_in[9];
  const float* W1 = (const float*)d_in[10];
  const float* W2 = (const float*)d_in[11];
  const float* g1 = (const float*)d_in[12];
  const float* b1 = (const float*)d_in[13];
  const float* g2 = (const float*)d_in[14];
  const float* b2 = (const float*)d_in[15];
  const float* fc_w = (const float*)d_in[16];
  const float* fc_b = (const float*)d_in[17];
  float* out = (float*)d_out;

  char* ws = (char*)d_ws;
  size_t off = 0;
  auto alloc = [&](size_t bytes) -> void* {
    void* p = ws + off;
    off = (off + bytes + 255) & ~(size_t)255;
    return p;
  };
  unsigned short* kv   = (unsigned short*)alloc((size_t)L_ * KVSZ * 2);  // per-layer
  int*            adj  = (int*)alloc((size_t)S_ * MAXDEG * 4);
  // adjcnt + bcnt contiguous -> one memset clears both
  int*            adjc = (int*)alloc((size_t)S_ * 4 + 8 * 32 * 4);
  unsigned*       bcnt = (unsigned*)(adjc + S_);
  unsigned short* wbf  = (unsigned short*)alloc((size_t)L_ * WLAYER * 2);

  hipMemsetAsync(adjc, 0, (size_t)S_ * 4 + 8 * 32 * 4, stream);
  setup_kernel<<<WBLK + ABLK, 256, 0, stream>>>(Wq, Wk, Wv, Wo, W1, W2, wbf,
                                                pcm, adj, adjc);
  mega_kernel<<<NBLK, 384, 0, stream>>>(r_t, src_embed, kv, wbf, g1, b1, g2, b2,
                                        t, time_tab, adj, adjc, fc_w, fc_b, out, bcnt);
}